// Round 5
// baseline (86.852 us; speedup 1.0000x reference)
//
#include <hip/hip_runtime.h>
#include <cstdint>

#define NB 32
#define NL 512
#define NE 256
#define NH 8
#define ND 64
#define NM 16384   // NB*NL
#define NHD 512    // NH*ND

using half8  = __attribute__((ext_vector_type(8))) _Float16;
using half4  = __attribute__((ext_vector_type(4))) _Float16;
using f32x4  = __attribute__((ext_vector_type(4))) float;
using f32x16 = __attribute__((ext_vector_type(16))) float;

__device__ __forceinline__ f32x4 mfma16(half8 a, half8 b, f32x4 c) {
    return __builtin_amdgcn_mfma_f32_16x16x32_f16(a, b, c, 0, 0, 0);
}
__device__ __forceinline__ f32x16 mfma32(half8 a, half8 b, f32x16 c) {
    return __builtin_amdgcn_mfma_f32_32x32x16_f16(a, b, c, 0, 0, 0);
}
// async global->LDS, 16B/lane; LDS dest = wave-uniform base + lane*16.
__device__ __forceinline__ void cp16_g2l(const void* g, void* l) {
    __builtin_amdgcn_global_load_lds(
        (const __attribute__((address_space(1))) void*)g,
        (__attribute__((address_space(3))) void*)l, 16, 0, 0);
}
// fast tanh: ~6 ops, 2 on TRANS pipe. |err| ~1e-6, invisible under f16.
__device__ __forceinline__ float fast_tanh(float x) {
    float xc = fminf(fmaxf(x, -9.f), 9.f);
    float t = __expf(2.f * xc);
    return (t - 1.f) * __builtin_amdgcn_rcpf(t + 1.f);
}

// ---------------- K0: fused weight repack + xph = f16(x+pos) ----------------
__global__ __launch_bounds__(256) void prep(
        const float* __restrict__ x, const float* __restrict__ pos,
        const float* __restrict__ Wq, const float* __restrict__ Wk,
        const float* __restrict__ Wv, const float* __restrict__ Wo,
        _Float16* __restrict__ wqkv, _Float16* __restrict__ woh,
        _Float16* __restrict__ xph) {
    int bid = blockIdx.x;
    if (bid < 2048) {
        int idx = bid * 256 + threadIdx.x;
        if (idx < 1536 * 256) {
            int n = idx >> 8, e = idx & 255;
            int s = n >> 9, h = (n >> 6) & 7, d = n & 63;
            const float* W = (s == 0) ? Wq : (s == 1) ? Wk : Wv;
            wqkv[idx] = (_Float16)W[(h * NE + e) * ND + d];
        } else {
            int j = idx - 1536 * 256;
            int e = j >> 9, f = j & 511;
            woh[j] = (_Float16)Wo[f * NE + e];
        }
    } else {
        int i = ((bid - 2048) * 256 + threadIdx.x) * 4;
        float4 xv = *(const float4*)(x + i);
        float4 pv = *(const float4*)(pos + (i & (NL * NE - 1)));
        half4 o;
        o[0] = (_Float16)(xv.x + pv.x);
        o[1] = (_Float16)(xv.y + pv.y);
        o[2] = (_Float16)(xv.z + pv.z);
        o[3] = (_Float16)(xv.w + pv.w);
        *(half4*)(xph + i) = o;
    }
}

// ---------------- K1: fused QKV projection GEMM ----------------
// q,k blocks (tn<8): Ct[n][m], tanh, store [token][c] (d-contig).
// v blocks (tn>=8): operand-swapped mfma -> D[token][c], store vT[c][token].
// BK=64, 128B LDS rows, XOR-swizzled via pre-swizzled global_load_lds source.
// Double-buffered LDS, prefetch-before-compute (T3-min 2-phase pipeline).
// Grid: XCD-chunked bijective remap (1536 = 8 x 12 x 16).
__global__ __launch_bounds__(256) void proj_gemm(
        const _Float16* __restrict__ wqkv, const _Float16* __restrict__ xph,
        _Float16* __restrict__ q_all, _Float16* __restrict__ k_all,
        _Float16* __restrict__ vT) {
    __shared__ _Float16 Alds[2][128 * 64];
    __shared__ _Float16 Blds[2][128 * 64];
    int tid = threadIdx.x;
    int w = tid >> 6, l = tid & 63;
    int bid = blockIdx.x;
    int xcd = bid & 7, local = bid >> 3;        // local in [0,192)
    int tn = local % 12;
    int tm = xcd * 16 + local / 12;             // contiguous tm chunk per XCD
    int wn = w >> 1, wm = w & 1;
    int m16 = l & 15, g = l >> 4;
    bool isv = (tn >= 8);
    int lrow8 = l >> 3;             // row within 8-row chunk
    int kc16 = (l & 7) ^ lrow8;     // pre-swizzled global 16B k-unit
    f32x4 acc[4][4] = {};

    const _Float16* Ag = wqkv + (size_t)tn * 128 * 256;
    const _Float16* Bg = xph + (size_t)tm * 128 * 256;

#define PROJ_STAGE(kt, buf)                                                   \
    _Pragma("unroll") for (int i = 0; i < 4; ++i) {                           \
        int cA = w * 4 + i;                                                   \
        int row = cA * 8 + lrow8;                                             \
        cp16_g2l(Ag + (size_t)row * 256 + (kt) * 64 + kc16 * 8,               \
                 &Alds[buf][cA * 512]);                                       \
        cp16_g2l(Bg + (size_t)row * 256 + (kt) * 64 + kc16 * 8,               \
                 &Blds[buf][cA * 512]);                                       \
    }

    PROJ_STAGE(0, 0);
    __syncthreads();
    int cur = 0;
    for (int kt = 0; kt < 4; ++kt) {
        if (kt < 3) { PROJ_STAGE(kt + 1, cur ^ 1); }
#pragma unroll
        for (int ks = 0; ks < 2; ++ks) {
            half8 af[4], bf[4];
#pragma unroll
            for (int f = 0; f < 4; ++f) {
                int ra = wn * 64 + f * 16 + m16;
                int rb = wm * 64 + f * 16 + m16;
                af[f] = *(const half8*)(&Alds[cur][ra * 64 + (((ks * 4 + g) ^ (ra & 7)) << 3)]);
                bf[f] = *(const half8*)(&Blds[cur][rb * 64 + (((ks * 4 + g) ^ (rb & 7)) << 3)]);
            }
            if (!isv) {
#pragma unroll
                for (int nf = 0; nf < 4; ++nf)
#pragma unroll
                    for (int mf = 0; mf < 4; ++mf)
                        acc[nf][mf] = mfma16(af[nf], bf[mf], acc[nf][mf]);
            } else {
#pragma unroll
                for (int nf = 0; nf < 4; ++nf)
#pragma unroll
                    for (int mf = 0; mf < 4; ++mf)
                        acc[nf][mf] = mfma16(bf[mf], af[nf], acc[nf][mf]);
            }
        }
        __syncthreads();
        cur ^= 1;
    }
#undef PROJ_STAGE
    if (!isv) {
        _Float16* dst = (tn < 4) ? q_all : k_all;
#pragma unroll
        for (int nf = 0; nf < 4; ++nf) {
            int c = (tn & 3) * 128 + wn * 64 + nf * 16 + g * 4;
#pragma unroll
            for (int mf = 0; mf < 4; ++mf) {
                int m = tm * 128 + wm * 64 + mf * 16 + m16;
                f32x4 v = acc[nf][mf];
                half4 hv;
#pragma unroll
                for (int r = 0; r < 4; ++r) hv[r] = (_Float16)fast_tanh(v[r]);
                *(half4*)(dst + (size_t)m * NHD + c) = hv;
            }
        }
    } else {
#pragma unroll
        for (int nf = 0; nf < 4; ++nf) {
            int c = (tn - 8) * 128 + wn * 64 + nf * 16 + m16;
#pragma unroll
            for (int mf = 0; mf < 4; ++mf) {
                int t0 = tm * 128 + wm * 64 + mf * 16 + g * 4;
                f32x4 v = acc[nf][mf];    // rows = tokens t0+r, col = c
                half4 hv;
#pragma unroll
                for (int r = 0; r < 4; ++r) hv[r] = (_Float16)fast_tanh(v[r]);
                *(half4*)(vT + (size_t)c * NM + t0) = hv;
            }
        }
    }
}

// ---------------- K2: flash attention, 32x32x16 MFMA ----------------
// 4 waves x 32 q-rows = 128 q/block; KV tiles of 64; S^T = mfma(K,Q) so each
// lane owns one q-row -> in-register softmax + 1 shuffle; defer-max (THR=8).
__global__ __launch_bounds__(256, 3) void attn_kernel(
        const _Float16* __restrict__ q_all, const _Float16* __restrict__ k_all,
        const _Float16* __restrict__ vT, _Float16* __restrict__ attn_out) {
    __shared__ _Float16 Klds[2][64 * 64];   // [key][d], unit^=(key&7)
    __shared__ _Float16 Vtlds[2][64 * 64];  // [d][key], unit^=(d&7)
    __shared__ _Float16 Plds[4][32 * 64];   // per-wave [q][key], unit^=(q&7)
    int tid = threadIdx.x;
    int w = tid >> 6, l = tid & 63;
    int l31 = l & 31, hi = l >> 5;
    int bid = blockIdx.x;
    int qt = bid & 3, h = (bid >> 2) & 7, b = bid >> 5;

    int qbase = qt * 128 + w * 32;
    half8 qf[4];   // B operand: [q=l31][d = ks*16 + hi*8]
    {
        const _Float16* qp = q_all + (size_t)(b * NL + qbase + l31) * NHD + h * ND + hi * 8;
#pragma unroll
        for (int ks = 0; ks < 4; ++ks) qf[ks] = *(const half8*)(qp + ks * 16);
    }

    f32x16 acc_o[2] = {};
    float mrow = -1e30f, lrow = 0.f;

    int st_row = tid >> 2;          // K: key / Vt: d
    int st_u0 = (tid & 3) * 2;      // two 16B units per thread
    const _Float16* kg = k_all + (size_t)(b * NL + st_row) * NHD + h * ND + st_u0 * 8;
    const _Float16* vg = vT + (size_t)(h * ND + st_row) * NM + b * NL + st_u0 * 8;
    int so0 = st_row * 64 + ((st_u0 ^ (st_row & 7)) << 3);
    int so1 = st_row * 64 + (((st_u0 + 1) ^ (st_row & 7)) << 3);

    uint4 kv0 = *(const uint4*)(kg);
    uint4 kv1 = *(const uint4*)(kg + 8);
    uint4 vv0 = *(const uint4*)(vg);
    uint4 vv1 = *(const uint4*)(vg + 8);
    *(uint4*)&Klds[0][so0] = kv0;   *(uint4*)&Klds[0][so1] = kv1;
    *(uint4*)&Vtlds[0][so0] = vv0;  *(uint4*)&Vtlds[0][so1] = vv1;
    __syncthreads();

    for (int kt = 0; kt < 8; ++kt) {
        int cur = kt & 1;
        if (kt < 7) {   // issue next-tile loads early (hide under compute)
            const _Float16* kp = kg + (size_t)(kt + 1) * 64 * NHD;
            const _Float16* vp = vg + (kt + 1) * 64;
            kv0 = *(const uint4*)(kp);      kv1 = *(const uint4*)(kp + 8);
            vv0 = *(const uint4*)(vp);      vv1 = *(const uint4*)(vp + 8);
        }
        // S^T = K Q^T : acc_s[kb2] rows=keys, cols=q
        f32x16 acc_s[2] = {};
        __builtin_amdgcn_s_setprio(1);
#pragma unroll
        for (int ks = 0; ks < 4; ++ks)
#pragma unroll
            for (int kb2 = 0; kb2 < 2; ++kb2) {
                int key = kb2 * 32 + l31;
                half8 kb = *(const half8*)(&Klds[cur][key * 64 + (((ks * 2 + hi) ^ (key & 7)) << 3)]);
                acc_s[kb2] = mfma32(kb, qf[ks], acc_s[kb2]);
            }
        __builtin_amdgcn_s_setprio(0);
        // online softmax, q = l31 per lane
        float mx = -1e30f;
#pragma unroll
        for (int kb2 = 0; kb2 < 2; ++kb2)
#pragma unroll
            for (int j = 0; j < 16; ++j) mx = fmaxf(mx, acc_s[kb2][j]);
        mx = fmaxf(mx, __shfl_xor(mx, 32));
        mx *= 0.125f;
        if (!__all(mx <= mrow + 8.f)) {   // defer-max: rescale rarely fires
            float mn = fmaxf(mrow, mx);
            float alpha = __expf(mrow - mn);
            mrow = mn;
            lrow *= alpha;
            float aq[16];
#pragma unroll
            for (int c = 0; c < 4; ++c)
#pragma unroll
                for (int r = 0; r < 4; ++r)
                    aq[c * 4 + r] = __shfl(alpha, c * 8 + hi * 4 + r);
#pragma unroll
            for (int d2 = 0; d2 < 2; ++d2)
#pragma unroll
                for (int j = 0; j < 16; ++j) acc_o[d2][j] *= aq[j];
        }
        float rs = 0.f;
#pragma unroll
        for (int kb2 = 0; kb2 < 2; ++kb2)
#pragma unroll
            for (int c = 0; c < 4; ++c) {
                half4 hv;
#pragma unroll
                for (int r = 0; r < 4; ++r) {
                    float p = __expf(acc_s[kb2][c * 4 + r] * 0.125f - mrow);
                    rs += p;
                    hv[r] = (_Float16)p;
                }
                int u = kb2 * 4 + c;   // keys u*8 + hi*4 + r
                *(half4*)(&Plds[w][l31 * 64 + ((u ^ (l31 & 7)) << 3) + hi * 4]) = hv;
            }
        rs += __shfl_xor(rs, 32);
        lrow += rs;
        // O += P V
        __builtin_amdgcn_s_setprio(1);
#pragma unroll
        for (int ks = 0; ks < 4; ++ks) {
            half8 pa = *(const half8*)(&Plds[w][l31 * 64 + (((ks * 2 + hi) ^ (l31 & 7)) << 3)]);
#pragma unroll
            for (int d2 = 0; d2 < 2; ++d2) {
                int d = d2 * 32 + l31;
                half8 vb = *(const half8*)(&Vtlds[cur][d * 64 + (((ks * 2 + hi) ^ (d & 7)) << 3)]);
                acc_o[d2] = mfma32(pa, vb, acc_o[d2]);
            }
        }
        __builtin_amdgcn_s_setprio(0);
        if (kt < 7) {   // write prefetched tile, single barrier per tile
            int nxt = cur ^ 1;
            *(uint4*)&Klds[nxt][so0] = kv0;   *(uint4*)&Klds[nxt][so1] = kv1;
            *(uint4*)&Vtlds[nxt][so0] = vv0;  *(uint4*)&Vtlds[nxt][so1] = vv1;
            __syncthreads();
        }
    }
    // epilogue: O[q][d], rows q from reg mapping, col d = d2*32 + l31
    size_t orow0 = (size_t)(b * NL + qbase);
#pragma unroll
    for (int c = 0; c < 4; ++c)
#pragma unroll
        for (int r = 0; r < 4; ++r) {
            int qrow = c * 8 + hi * 4 + r;
            float inv = 1.f / __shfl(lrow, qrow);
#pragma unroll
            for (int d2 = 0; d2 < 2; ++d2)
                attn_out[(orow0 + qrow) * NHD + h * ND + d2 * 32 + l31] =
                    (_Float16)(acc_o[d2][c * 4 + r] * inv);
        }
}

// ---------------- K3: output projection + f16 tanh residual ----------------
// tile 128e x 64m -> 512 blocks. BK=64, swizzled dbuf LDS, 2-phase pipeline.
// Residual from xph (f16 x+pos) -- saves the fp32 x re-read.
__global__ __launch_bounds__(256) void final_gemm(
        const _Float16* __restrict__ woh, const _Float16* __restrict__ attn,
        const _Float16* __restrict__ xph, float* __restrict__ out) {
    __shared__ _Float16 Alds[2][128 * 64];
    __shared__ _Float16 Blds[2][64 * 64];
    int tid = threadIdx.x;
    int w = tid >> 6, l = tid & 63;
    int tn = blockIdx.x & 1, tm = blockIdx.x >> 1;
    int wn = w >> 1, wm = w & 1;
    int m16 = l & 15, g = l >> 4;
    int lrow8 = l >> 3;
    int kc16 = (l & 7) ^ lrow8;
    f32x4 acc[4][2] = {};

    const _Float16* Ag = woh + (size_t)tn * 128 * 512;
    const _Float16* Bg = attn + (size_t)tm * 64 * 512;

#define FIN_STAGE(kt, buf)                                                    \
    _Pragma("unroll") for (int i = 0; i < 4; ++i) {                           \
        int cA = w * 4 + i;                                                   \
        int row = cA * 8 + lrow8;                                             \
        cp16_g2l(Ag + (size_t)row * 512 + (kt) * 64 + kc16 * 8,               \
                 &Alds[buf][cA * 512]);                                       \
    }                                                                         \
    _Pragma("unroll") for (int i = 0; i < 2; ++i) {                           \
        int cB = w * 2 + i;                                                   \
        int row = cB * 8 + lrow8;                                             \
        cp16_g2l(Bg + (size_t)row * 512 + (kt) * 64 + kc16 * 8,               \
                 &Blds[buf][cB * 512]);                                       \
    }

    FIN_STAGE(0, 0);
    __syncthreads();
    int cur = 0;
    for (int kt = 0; kt < 8; ++kt) {
        if (kt < 7) { FIN_STAGE(kt + 1, cur ^ 1); }
#pragma unroll
        for (int ks = 0; ks < 2; ++ks) {
            half8 af[4], bf[2];
#pragma unroll
            for (int f = 0; f < 4; ++f) {
                int ra = wn * 64 + f * 16 + m16;
                af[f] = *(const half8*)(&Alds[cur][ra * 64 + (((ks * 4 + g) ^ (ra & 7)) << 3)]);
            }
#pragma unroll
            for (int f = 0; f < 2; ++f) {
                int rb = wm * 32 + f * 16 + m16;
                bf[f] = *(const half8*)(&Blds[cur][rb * 64 + (((ks * 4 + g) ^ (rb & 7)) << 3)]);
            }
#pragma unroll
            for (int nf = 0; nf < 4; ++nf)
#pragma unroll
                for (int mf = 0; mf < 2; ++mf)
                    acc[nf][mf] = mfma16(af[nf], bf[mf], acc[nf][mf]);
        }
        __syncthreads();
        cur ^= 1;
    }
#undef FIN_STAGE
#pragma unroll
    for (int nf = 0; nf < 4; ++nf) {
        int e = tn * 128 + wn * 64 + nf * 16 + g * 4;
#pragma unroll
        for (int mf = 0; mf < 2; ++mf) {
            int m = tm * 64 + wm * 32 + mf * 16 + m16;
            half4 hx = *(const half4*)(xph + (size_t)m * NE + e);
            f32x4 v = acc[nf][mf];
            float4 o;
            o.x = v[0] + fast_tanh((float)hx[0]);
            o.y = v[1] + fast_tanh((float)hx[1]);
            o.z = v[2] + fast_tanh((float)hx[2]);
            o.w = v[3] + fast_tanh((float)hx[3]);
            *(float4*)(out + (size_t)m * NE + e) = o;
        }
    }
}

extern "C" void kernel_launch(void* const* d_in, const int* in_sizes, int n_in,
                              void* d_out, int out_size, void* d_ws, size_t ws_size,
                              hipStream_t stream) {
    const float* x   = (const float*)d_in[0];
    const float* pos = (const float*)d_in[1];
    const float* Wq  = (const float*)d_in[2];
    const float* Wk  = (const float*)d_in[3];
    const float* Wv  = (const float*)d_in[4];
    const float* Wo  = (const float*)d_in[5];
    float* out = (float*)d_out;

    char* ws = (char*)d_ws;
    _Float16* xph   = (_Float16*)(ws);              //  8,388,608 B
    _Float16* wqkv  = (_Float16*)(ws + 8388608);    //    786,432 B
    _Float16* woh   = (_Float16*)(ws + 9175040);    //    262,144 B
    _Float16* q_all = (_Float16*)(ws + 9437184);    // 16,777,216 B
    _Float16* k_all = (_Float16*)(ws + 26214400);   // 16,777,216 B
    _Float16* vT    = (_Float16*)(ws + 42991616);   // 16,777,216 B [c][token]
    _Float16* attn  = (_Float16*)(ws + 59768832);   // 16,777,216 B

    prep<<<dim3(6144), dim3(256), 0, stream>>>(x, pos, Wq, Wk, Wv, Wo, wqkv, woh, xph);
    proj_gemm<<<dim3(12 * 128), dim3(256), 0, stream>>>(wqkv, xph, q_all, k_all, vT);
    attn_kernel<<<dim3(1024), dim3(256), 0, stream>>>(q_all, k_all, vT, attn);
    final_gemm<<<dim3(512), dim3(256), 0, stream>>>(woh, attn, xph, out);
}

// Round 9
// 85.364 us; speedup vs baseline: 1.0174x; 1.0174x over previous
//
#include <hip/hip_runtime.h>
#include <cstdint>

#define NB 32
#define NL 512
#define NE 256
#define NH 8
#define ND 64
#define NM 16384   // NB*NL
#define NHD 512    // NH*ND

using half8  = __attribute__((ext_vector_type(8))) _Float16;
using half4  = __attribute__((ext_vector_type(4))) _Float16;
using f32x4  = __attribute__((ext_vector_type(4))) float;
using f32x16 = __attribute__((ext_vector_type(16))) float;
using u32x2  = __attribute__((ext_vector_type(2))) unsigned int;

__device__ __forceinline__ f32x4 mfma16(half8 a, half8 b, f32x4 c) {
    return __builtin_amdgcn_mfma_f32_16x16x32_f16(a, b, c, 0, 0, 0);
}
__device__ __forceinline__ f32x16 mfma32(half8 a, half8 b, f32x16 c) {
    return __builtin_amdgcn_mfma_f32_32x32x16_f16(a, b, c, 0, 0, 0);
}
// async global->LDS, 16B/lane; LDS dest = wave-uniform base + lane*16.
__device__ __forceinline__ void cp16_g2l(const void* g, void* l) {
    __builtin_amdgcn_global_load_lds(
        (const __attribute__((address_space(1))) void*)g,
        (__attribute__((address_space(3))) void*)l, 16, 0, 0);
}
// 2^x on the TRANS pipe (v_exp_f32), no libm dependence.
__device__ __forceinline__ float exp2fast(float x) {
    return __builtin_amdgcn_exp2f(x);
}
// fast tanh: ~6 ops, 2 on TRANS pipe. |err| ~1e-6, invisible under f16.
__device__ __forceinline__ float fast_tanh(float x) {
    float xc = fminf(fmaxf(x, -9.f), 9.f);
    float t = exp2fast(xc * 2.88539008178f);   // e^(2x) = 2^(2x*log2e)
    return (t - 1.f) * __builtin_amdgcn_rcpf(t + 1.f);
}
// pack two f32 -> two f16 in one u32 (v_cvt_pkrtz_f16_f32)
__device__ __forceinline__ uint32_t pk16(float a, float b) {
    auto h2 = __builtin_amdgcn_cvt_pkrtz(a, b);
    return __builtin_bit_cast(uint32_t, h2);
}

// ---------------- K0: fused weight repack + xph = f16(x+pos) ----------------
__global__ __launch_bounds__(256) void prep(
        const float* __restrict__ x, const float* __restrict__ pos,
        const float* __restrict__ Wq, const float* __restrict__ Wk,
        const float* __restrict__ Wv, const float* __restrict__ Wo,
        _Float16* __restrict__ wqkv, _Float16* __restrict__ woh,
        _Float16* __restrict__ xph) {
    int bid = blockIdx.x;
    if (bid < 2048) {
        int idx = bid * 256 + threadIdx.x;
        if (idx < 1536 * 256) {
            int n = idx >> 8, e = idx & 255;
            int s = n >> 9, h = (n >> 6) & 7, d = n & 63;
            const float* W = (s == 0) ? Wq : (s == 1) ? Wk : Wv;
            wqkv[idx] = (_Float16)W[(h * NE + e) * ND + d];
        } else {
            int j = idx - 1536 * 256;
            int e = j >> 9, f = j & 511;
            woh[j] = (_Float16)Wo[f * NE + e];
        }
    } else {
        int i = ((bid - 2048) * 256 + threadIdx.x) * 4;
        float4 xv = *(const float4*)(x + i);
        float4 pv = *(const float4*)(pos + (i & (NL * NE - 1)));
        half4 o;
        o[0] = (_Float16)(xv.x + pv.x);
        o[1] = (_Float16)(xv.y + pv.y);
        o[2] = (_Float16)(xv.z + pv.z);
        o[3] = (_Float16)(xv.w + pv.w);
        *(half4*)(xph + i) = o;
    }
}

// ---------------- K1: fused QKV projection GEMM ----------------
// q,k blocks (tn<8): Ct[n][m], tanh, store [token][c] (d-contig).
// v blocks (tn>=8): operand-swapped mfma -> D[token][c], store vT[c][token].
// BK=64, 128B LDS rows, XOR-swizzled via pre-swizzled global_load_lds source.
// Double-buffered LDS, prefetch-before-compute (T3-min 2-phase pipeline).
// Grid: XCD-chunked bijective remap (1536 = 8 x 12 x 16).
__global__ __launch_bounds__(256) void proj_gemm(
        const _Float16* __restrict__ wqkv, const _Float16* __restrict__ xph,
        _Float16* __restrict__ q_all, _Float16* __restrict__ k_all,
        _Float16* __restrict__ vT) {
    __shared__ _Float16 Alds[2][128 * 64];
    __shared__ _Float16 Blds[2][128 * 64];
    int tid = threadIdx.x;
    int w = tid >> 6, l = tid & 63;
    int bid = blockIdx.x;
    int xcd = bid & 7, local = bid >> 3;        // local in [0,192)
    int tn = local % 12;
    int tm = xcd * 16 + local / 12;             // contiguous tm chunk per XCD
    int wn = w >> 1, wm = w & 1;
    int m16 = l & 15, g = l >> 4;
    bool isv = (tn >= 8);
    int lrow8 = l >> 3;             // row within 8-row chunk
    int kc16 = (l & 7) ^ lrow8;     // pre-swizzled global 16B k-unit
    f32x4 acc[4][4] = {};

    const _Float16* Ag = wqkv + (size_t)tn * 128 * 256;
    const _Float16* Bg = xph + (size_t)tm * 128 * 256;

#define PROJ_STAGE(kt, buf)                                                   \
    _Pragma("unroll") for (int i = 0; i < 4; ++i) {                           \
        int cA = w * 4 + i;                                                   \
        int row = cA * 8 + lrow8;                                             \
        cp16_g2l(Ag + (size_t)row * 256 + (kt) * 64 + kc16 * 8,               \
                 &Alds[buf][cA * 512]);                                       \
        cp16_g2l(Bg + (size_t)row * 256 + (kt) * 64 + kc16 * 8,               \
                 &Blds[buf][cA * 512]);                                       \
    }

    PROJ_STAGE(0, 0);
    __syncthreads();
    int cur = 0;
    for (int kt = 0; kt < 4; ++kt) {
        if (kt < 3) { PROJ_STAGE(kt + 1, cur ^ 1); }
#pragma unroll
        for (int ks = 0; ks < 2; ++ks) {
            half8 af[4], bf[4];
#pragma unroll
            for (int f = 0; f < 4; ++f) {
                int ra = wn * 64 + f * 16 + m16;
                int rb = wm * 64 + f * 16 + m16;
                af[f] = *(const half8*)(&Alds[cur][ra * 64 + (((ks * 4 + g) ^ (ra & 7)) << 3)]);
                bf[f] = *(const half8*)(&Blds[cur][rb * 64 + (((ks * 4 + g) ^ (rb & 7)) << 3)]);
            }
            if (!isv) {
#pragma unroll
                for (int nf = 0; nf < 4; ++nf)
#pragma unroll
                    for (int mf = 0; mf < 4; ++mf)
                        acc[nf][mf] = mfma16(af[nf], bf[mf], acc[nf][mf]);
            } else {
#pragma unroll
                for (int nf = 0; nf < 4; ++nf)
#pragma unroll
                    for (int mf = 0; mf < 4; ++mf)
                        acc[nf][mf] = mfma16(bf[mf], af[nf], acc[nf][mf]);
            }
        }
        __syncthreads();
        cur ^= 1;
    }
#undef PROJ_STAGE
    if (!isv) {
        _Float16* dst = (tn < 4) ? q_all : k_all;
#pragma unroll
        for (int nf = 0; nf < 4; ++nf) {
            int c = (tn & 3) * 128 + wn * 64 + nf * 16 + g * 4;
#pragma unroll
            for (int mf = 0; mf < 4; ++mf) {
                int m = tm * 128 + wm * 64 + mf * 16 + m16;
                f32x4 v = acc[nf][mf];
                half4 hv;
#pragma unroll
                for (int r = 0; r < 4; ++r) hv[r] = (_Float16)fast_tanh(v[r]);
                *(half4*)(dst + (size_t)m * NHD + c) = hv;
            }
        }
    } else {
#pragma unroll
        for (int nf = 0; nf < 4; ++nf) {
            int c = (tn - 8) * 128 + wn * 64 + nf * 16 + m16;
#pragma unroll
            for (int mf = 0; mf < 4; ++mf) {
                int t0 = tm * 128 + wm * 64 + mf * 16 + g * 4;
                f32x4 v = acc[nf][mf];    // rows = tokens t0+r, col = c
                half4 hv;
#pragma unroll
                for (int r = 0; r < 4; ++r) hv[r] = (_Float16)fast_tanh(v[r]);
                *(half4*)(vT + (size_t)c * NM + t0) = hv;
            }
        }
    }
}

// ---------------- K2: flash attention, 32x32x16 MFMA ----------------
// 4 waves x 32 q-rows = 128 q/block; KV tiles of 64; S^T = mfma(K,Q) so each
// lane owns one q-row -> in-register softmax; defer-max (THR=8).
// T12: P stays in registers -- cvt_pkrtz pack + permlane32_swap assembles the
// PV A-fragments directly from acc_s (no P LDS round-trip).
// Derivation (ISA: swap(a,b) -> ret0={a_lo, b_lo->hi}, ret1={a_hi->lo, b_hi}):
// lane(q=l31,hi) owns key 32*kb2+8a+4*hi+b in acc_s[kb2] reg 4a+b.
// pa[ks] lane(q,hi_pv) elem e needs key 16*ks+8*hi_pv+e:
//   owner block a' = 2*(ks&1)+hi_pv; e<4 from hi'=0 owner, e>=4 from hi'=1.
// swap(even-block word p, odd-block word p): ret[0] = w_p, ret[1] = w_{p+2}
// (verified by lane enumeration for hi_pv=0 and hi_pv=1, all words).
__global__ __launch_bounds__(256, 3) void attn_kernel(
        const _Float16* __restrict__ q_all, const _Float16* __restrict__ k_all,
        const _Float16* __restrict__ vT, _Float16* __restrict__ attn_out) {
    __shared__ _Float16 Klds[2][64 * 64];   // [key][d], unit^=(key&7)
    __shared__ _Float16 Vtlds[2][64 * 64];  // [d][key], unit^=(d&7)
    int tid = threadIdx.x;
    int w = tid >> 6, l = tid & 63;
    int l31 = l & 31, hi = l >> 5;
    int bid = blockIdx.x;
    int qt = bid & 3, h = (bid >> 2) & 7, b = bid >> 5;
    const float C1 = 0.125f * 1.44269504089f;   // scale * log2(e)

    int qbase = qt * 128 + w * 32;
    half8 qf[4];   // B operand: [q=l31][d = ks*16 + hi*8]
    {
        const _Float16* qp = q_all + (size_t)(b * NL + qbase + l31) * NHD + h * ND + hi * 8;
#pragma unroll
        for (int ks = 0; ks < 4; ++ks) qf[ks] = *(const half8*)(qp + ks * 16);
    }

    f32x16 acc_o[2] = {};
    float mrow = -1e30f, lrow = 0.f;

    int st_row = tid >> 2;          // K: key / Vt: d
    int st_u0 = (tid & 3) * 2;      // two 16B units per thread
    const _Float16* kg = k_all + (size_t)(b * NL + st_row) * NHD + h * ND + st_u0 * 8;
    const _Float16* vg = vT + (size_t)(h * ND + st_row) * NM + b * NL + st_u0 * 8;
    int so0 = st_row * 64 + ((st_u0 ^ (st_row & 7)) << 3);
    int so1 = st_row * 64 + (((st_u0 + 1) ^ (st_row & 7)) << 3);

    uint4 kv0 = *(const uint4*)(kg);
    uint4 kv1 = *(const uint4*)(kg + 8);
    uint4 vv0 = *(const uint4*)(vg);
    uint4 vv1 = *(const uint4*)(vg + 8);
    *(uint4*)&Klds[0][so0] = kv0;   *(uint4*)&Klds[0][so1] = kv1;
    *(uint4*)&Vtlds[0][so0] = vv0;  *(uint4*)&Vtlds[0][so1] = vv1;
    __syncthreads();

    for (int kt = 0; kt < 8; ++kt) {
        int cur = kt & 1;
        if (kt < 7) {   // issue next-tile loads early (hide under compute)
            const _Float16* kp = kg + (size_t)(kt + 1) * 64 * NHD;
            const _Float16* vp = vg + (kt + 1) * 64;
            kv0 = *(const uint4*)(kp);      kv1 = *(const uint4*)(kp + 8);
            vv0 = *(const uint4*)(vp);      vv1 = *(const uint4*)(vp + 8);
        }
        // S^T = K Q^T : acc_s[kb2] rows=keys, cols=q
        f32x16 acc_s[2] = {};
        __builtin_amdgcn_s_setprio(1);
#pragma unroll
        for (int ks = 0; ks < 4; ++ks)
#pragma unroll
            for (int kb2 = 0; kb2 < 2; ++kb2) {
                int key = kb2 * 32 + l31;
                half8 kb = *(const half8*)(&Klds[cur][key * 64 + (((ks * 2 + hi) ^ (key & 7)) << 3)]);
                acc_s[kb2] = mfma32(kb, qf[ks], acc_s[kb2]);
            }
        __builtin_amdgcn_s_setprio(0);
        // online softmax, q = l31 per lane
        float mx = -1e30f;
#pragma unroll
        for (int kb2 = 0; kb2 < 2; ++kb2)
#pragma unroll
            for (int j = 0; j < 16; ++j) mx = fmaxf(mx, acc_s[kb2][j]);
        mx = fmaxf(mx, __shfl_xor(mx, 32));
        mx *= 0.125f;
        if (!__all(mx <= mrow + 8.f)) {   // defer-max: rescale rarely fires
            float mn = fmaxf(mrow, mx);
            float alpha = exp2fast((mrow - mn) * 1.44269504089f);
            mrow = mn;
            lrow *= alpha;
            float aq[16];
#pragma unroll
            for (int c = 0; c < 4; ++c)
#pragma unroll
                for (int r = 0; r < 4; ++r)
                    aq[c * 4 + r] = __shfl(alpha, c * 8 + hi * 4 + r);
#pragma unroll
            for (int d2 = 0; d2 < 2; ++d2)
#pragma unroll
                for (int j = 0; j < 16; ++j) acc_o[d2][j] *= aq[j];
        }
        // p = exp2(fma(s, C1, -ml)); pack pairs to f16 words in regs
        float ml = mrow * 1.44269504089f;
        float rs = 0.f;
        uint32_t cw[2][4][2];
#pragma unroll
        for (int kb2 = 0; kb2 < 2; ++kb2)
#pragma unroll
            for (int a = 0; a < 4; ++a)
#pragma unroll
                for (int p = 0; p < 2; ++p) {
                    float p0 = exp2fast(fmaf(acc_s[kb2][4 * a + 2 * p],     C1, -ml));
                    float p1 = exp2fast(fmaf(acc_s[kb2][4 * a + 2 * p + 1], C1, -ml));
                    rs += p0 + p1;
                    cw[kb2][a][p] = pk16(p0, p1);
                }
        rs += __shfl_xor(rs, 32);
        lrow += rs;
        // O += P V   (pa assembled in-register via permlane32_swap)
        __builtin_amdgcn_s_setprio(1);
#pragma unroll
        for (int ks = 0; ks < 4; ++ks) {
            int kb2 = ks >> 1, s = ks & 1;
            u32x2 r0 = __builtin_amdgcn_permlane32_swap(
                cw[kb2][2 * s][0], cw[kb2][2 * s + 1][0], false, false);
            u32x2 r1 = __builtin_amdgcn_permlane32_swap(
                cw[kb2][2 * s][1], cw[kb2][2 * s + 1][1], false, false);
            union { uint32_t u[4]; half8 h; } pu;
            pu.u[0] = r0[0];  pu.u[1] = r1[0];   // e=0..3 (hi'=0 owner)
            pu.u[2] = r0[1];  pu.u[3] = r1[1];   // e=4..7 (hi'=1 owner)
#pragma unroll
            for (int d2 = 0; d2 < 2; ++d2) {
                int d = d2 * 32 + l31;
                half8 vb = *(const half8*)(&Vtlds[cur][d * 64 + (((ks * 2 + hi) ^ (d & 7)) << 3)]);
                acc_o[d2] = mfma32(pu.h, vb, acc_o[d2]);
            }
        }
        __builtin_amdgcn_s_setprio(0);
        if (kt < 7) {   // write prefetched tile, single barrier per tile
            int nxt = cur ^ 1;
            *(uint4*)&Klds[nxt][so0] = kv0;   *(uint4*)&Klds[nxt][so1] = kv1;
            *(uint4*)&Vtlds[nxt][so0] = vv0;  *(uint4*)&Vtlds[nxt][so1] = vv1;
            __syncthreads();
        }
    }
    // epilogue: O[q][d], rows q from reg mapping, col d = d2*32 + l31
    size_t orow0 = (size_t)(b * NL + qbase);
#pragma unroll
    for (int c = 0; c < 4; ++c)
#pragma unroll
        for (int r = 0; r < 4; ++r) {
            int qrow = c * 8 + hi * 4 + r;
            float inv = 1.f / __shfl(lrow, qrow);
#pragma unroll
            for (int d2 = 0; d2 < 2; ++d2)
                attn_out[(orow0 + qrow) * NHD + h * ND + d2 * 32 + l31] =
                    (_Float16)(acc_o[d2][c * 4 + r] * inv);
        }
}

// ---------------- K3: output projection + f16 tanh residual ----------------
// tile 128e x 64m -> 512 blocks. BK=64, swizzled dbuf LDS, 2-phase pipeline.
// Residual from xph (f16 x+pos) -- saves the fp32 x re-read.
__global__ __launch_bounds__(256) void final_gemm(
        const _Float16* __restrict__ woh, const _Float16* __restrict__ attn,
        const _Float16* __restrict__ xph, float* __restrict__ out) {
    __shared__ _Float16 Alds[2][128 * 64];
    __shared__ _Float16 Blds[2][64 * 64];
    int tid = threadIdx.x;
    int w = tid >> 6, l = tid & 63;
    int tn = blockIdx.x & 1, tm = blockIdx.x >> 1;
    int wn = w >> 1, wm = w & 1;
    int m16 = l & 15, g = l >> 4;
    int lrow8 = l >> 3;
    int kc16 = (l & 7) ^ lrow8;
    f32x4 acc[4][2] = {};

    const _Float16* Ag = woh + (size_t)tn * 128 * 512;
    const _Float16* Bg = attn + (size_t)tm * 64 * 512;

#define FIN_STAGE(kt, buf)                                                    \
    _Pragma("unroll") for (int i = 0; i < 4; ++i) {                           \
        int cA = w * 4 + i;                                                   \
        int row = cA * 8 + lrow8;                                             \
        cp16_g2l(Ag + (size_t)row * 512 + (kt) * 64 + kc16 * 8,               \
                 &Alds[buf][cA * 512]);                                       \
    }                                                                         \
    _Pragma("unroll") for (int i = 0; i < 2; ++i) {                           \
        int cB = w * 2 + i;                                                   \
        int row = cB * 8 + lrow8;                                             \
        cp16_g2l(Bg + (size_t)row * 512 + (kt) * 64 + kc16 * 8,               \
                 &Blds[buf][cB * 512]);                                       \
    }

    FIN_STAGE(0, 0);
    __syncthreads();
    int cur = 0;
    for (int kt = 0; kt < 8; ++kt) {
        if (kt < 7) { FIN_STAGE(kt + 1, cur ^ 1); }
#pragma unroll
        for (int ks = 0; ks < 2; ++ks) {
            half8 af[4], bf[2];
#pragma unroll
            for (int f = 0; f < 4; ++f) {
                int ra = wn * 64 + f * 16 + m16;
                af[f] = *(const half8*)(&Alds[cur][ra * 64 + (((ks * 4 + g) ^ (ra & 7)) << 3)]);
            }
#pragma unroll
            for (int f = 0; f < 2; ++f) {
                int rb = wm * 32 + f * 16 + m16;
                bf[f] = *(const half8*)(&Blds[cur][rb * 64 + (((ks * 4 + g) ^ (rb & 7)) << 3)]);
            }
#pragma unroll
            for (int nf = 0; nf < 4; ++nf)
#pragma unroll
                for (int mf = 0; mf < 2; ++mf)
                    acc[nf][mf] = mfma16(af[nf], bf[mf], acc[nf][mf]);
        }
        __syncthreads();
        cur ^= 1;
    }
#undef FIN_STAGE
#pragma unroll
    for (int nf = 0; nf < 4; ++nf) {
        int e = tn * 128 + wn * 64 + nf * 16 + g * 4;
#pragma unroll
        for (int mf = 0; mf < 2; ++mf) {
            int m = tm * 64 + wm * 32 + mf * 16 + m16;
            half4 hx = *(const half4*)(xph + (size_t)m * NE + e);
            f32x4 v = acc[nf][mf];
            float4 o;
            o.x = v[0] + fast_tanh((float)hx[0]);
            o.y = v[1] + fast_tanh((float)hx[1]);
            o.z = v[2] + fast_tanh((float)hx[2]);
            o.w = v[3] + fast_tanh((float)hx[3]);
            *(float4*)(out + (size_t)m * NE + e) = o;
        }
    }
}

extern "C" void kernel_launch(void* const* d_in, const int* in_sizes, int n_in,
                              void* d_out, int out_size, void* d_ws, size_t ws_size,
                              hipStream_t stream) {
    const float* x   = (const float*)d_in[0];
    const float* pos = (const float*)d_in[1];
    const float* Wq  = (const float*)d_in[2];
    const float* Wk  = (const float*)d_in[3];
    const float* Wv  = (const float*)d_in[4];
    const float* Wo  = (const float*)d_in[5];
    float* out = (float*)d_out;

    char* ws = (char*)d_ws;
    _Float16* xph   = (_Float16*)(ws);              //  8,388,608 B
    _Float16* wqkv  = (_Float16*)(ws + 8388608);    //    786,432 B
    _Float16* woh   = (_Float16*)(ws + 9175040);    //    262,144 B
    _Float16* q_all = (_Float16*)(ws + 9437184);    // 16,777,216 B
    _Float16* k_all = (_Float16*)(ws + 26214400);   // 16,777,216 B
    _Float16* vT    = (_Float16*)(ws + 42991616);   // 16,777,216 B [c][token]
    _Float16* attn  = (_Float16*)(ws + 59768832);   // 16,777,216 B

    prep<<<dim3(6144), dim3(256), 0, stream>>>(x, pos, Wq, Wk, Wv, Wo, wqkv, woh, xph);
    proj_gemm<<<dim3(12 * 128), dim3(256), 0, stream>>>(wqkv, xph, q_all, k_all, vT);
    attn_kernel<<<dim3(1024), dim3(256), 0, stream>>>(q_all, k_all, vT, attn);
    final_gemm<<<dim3(512), dim3(256), 0, stream>>>(woh, attn, xph, out);
}